// Round 9
// baseline (230.173 us; speedup 1.0000x reference)
//
#include <hip/hip_runtime.h>
#include <hip/hip_bf16.h>

#define BATCH 4
#define SEQ   4096
#define DIM   64
#define TK    32               // keys per LDS tile (16 KB dbuf -> 8 blocks/CU)
#define TOTQ  (BATCH * SEQ)    // 16384
#define NSEG  16               // key segments (grid 2048 = 8 blocks/CU)
#define LOG2E 1.4426950408889634f

#if __has_builtin(__builtin_amdgcn_mfma_f32_16x16x16bf16_1k)
#define HAVE_1K 1
#else
#define HAVE_1K 0              // inline-asm v_mfma_f32_16x16x16_bf16 (ISA-confirmed gfx950)
#endif

#if __has_builtin(__builtin_amdgcn_exp2f)
#define EXP2(x) __builtin_amdgcn_exp2f(x)
#else
#define EXP2(x) exp2f(x)
#endif

typedef __attribute__((ext_vector_type(8))) short bf16x8;   // 4 VGPR frag (x32 MFMA A/B)
typedef __attribute__((ext_vector_type(4))) short bf16x4;   // 2 VGPR frag (x16 MFMA A/B)
typedef __attribute__((ext_vector_type(4))) float f32x4;    // MFMA C/D frag

#define AS1 __attribute__((address_space(1)))
#define AS3 __attribute__((address_space(3)))

static __device__ __forceinline__ short f2bf(float x) {
    __hip_bfloat16 h = __float2bfloat16(x);
    return *reinterpret_cast<short*>(&h);
}
static __device__ __forceinline__ float bf2f(short s) {
    unsigned int u = ((unsigned int)(unsigned short)s) << 16;
    float f; __builtin_memcpy(&f, &u, 4); return f;
}
static __device__ __forceinline__ int pk2bf(float lo, float hi) {
    __hip_bfloat162 t = __float22bfloat162_rn(make_float2(lo, hi));
    int r; __builtin_memcpy(&r, &t, 4); return r;
}
static __device__ __forceinline__ bf16x4 mk4(const f32x4& s) {
    int2 t = make_int2(pk2bf(s[0], s[1]), pk2bf(s[2], s[3]));
    bf16x4 r; __builtin_memcpy(&r, &t, 8); return r;
}
static __device__ __forceinline__ f32x4 mfma16(bf16x4 a, bf16x4 b, f32x4 c) {
#if HAVE_1K
    return __builtin_amdgcn_mfma_f32_16x16x16bf16_1k(a, b, c, 0, 0, 0);
#else
    asm("v_mfma_f32_16x16x16_bf16 %0, %1, %2, %0" : "+v"(c) : "v"(a), "v"(b));
    return c;
#endif
}
static __device__ __forceinline__ void async16(const short* g, short* l) {
    __builtin_amdgcn_global_load_lds((const AS1 unsigned int*)g,
                                     (AS3 unsigned int*)l, 16, 0, 0);
}

// ---------------- pack pre-pass ----------------
// Kp: bf16 row-major [B*S][64], granule swizzle g' = (d>>3) ^ (row&7)  (unchanged).
// Vtp: bf16 per-32-key tile [tile][d(64)][32], V' = mask*V, pair-interleaved:
//   granule G (=reader quad) holds e=v*4+j -> key_local = v*16 + G*4 + j
//   stored at granule slot Gs = G ^ ((d>>1)&3)  (2-way-free reads, rows = 64 B).
__global__ __launch_bounds__(256)
void pack_kv(const float* __restrict__ kg, const float* __restrict__ vg,
             const float* __restrict__ mg,
             short* __restrict__ kp, short* __restrict__ vtp)
{
    if (blockIdx.x < 256) {                            // ---- K: 4 float4 / thread ----
        #pragma unroll
        for (int i = 0; i < 4; ++i) {
            const int unit = blockIdx.x * 1024 + i * 256 + threadIdx.x;
            const int row = unit >> 4;
            const int d0  = (unit & 15) * 4;
            f32x4 kv = *reinterpret_cast<const f32x4*>(kg + (size_t)row * DIM + d0);
            short4 ks;
            ks.x = f2bf(kv[0]); ks.y = f2bf(kv[1]); ks.z = f2bf(kv[2]); ks.w = f2bf(kv[3]);
            const int gs = (d0 >> 3) ^ (row & 7);
            *reinterpret_cast<short4*>(kp + (size_t)row * DIM + gs * 8 + (d0 & 7)) = ks;
        }
    } else {                                           // ---- V: one 64-key chunk / block ----
        __shared__ float Vl[64][66];
        __shared__ float Ml[64];
        const int t64 = blockIdx.x - 256;
        const float* src = vg + (size_t)t64 * 64 * DIM;
        const int tid = threadIdx.x;
        #pragma unroll
        for (int i = 0; i < 4; ++i) {
            int idx = i * 256 + tid;
            int key = idx >> 4, part = idx & 15;
            f32x4 vv = *reinterpret_cast<const f32x4*>(src + (size_t)key * DIM + part * 4);
            float2* p0 = reinterpret_cast<float2*>(&Vl[key][part * 4]);
            p0[0] = make_float2(vv[0], vv[1]);
            p0[1] = make_float2(vv[2], vv[3]);
        }
        if (tid < 64) Ml[tid] = mg[(size_t)t64 * 64 + tid];
        __syncthreads();
        // 512 granule-writes (2 sub-tiles x 64 d x 4 G), 2 per thread
        #pragma unroll
        for (int i = 0; i < 2; ++i) {
            const int gid = i * 256 + tid;
            const int t2 = gid >> 8;          // 32-key sub-tile
            const int d  = (gid >> 2) & 63;
            const int G  = gid & 3;
            alignas(16) short s8[8];
            #pragma unroll
            for (int e = 0; e < 8; ++e) {     // e = v*4 + j
                const int v = e >> 2, j = e & 3;
                const int key = t2 * 32 + v * 16 + G * 4 + j;
                s8[e] = f2bf(Vl[key][d] * Ml[key]);
            }
            const int Gs = G ^ ((d >> 1) & 3);
            short* dst = vtp + ((size_t)t64 * 2 + t2) * (TK * DIM) + d * TK + Gs * 8;
            *reinterpret_cast<int4*>(dst) = *reinterpret_cast<const int4*>(s8);
        }
    }
}

// ---------------- main attention kernel (R6 lean core @ 8 blocks/CU) ----------------
// S^T orientation; Q pre-scaled 0.125*log2e so p = exp2(s); V pre-masked;
// PV via 16x16x16 MFMA (S^T C-layout == P^T B-layout, no cross-lane move).
// Block index order puts all 32 blocks sharing one (b,seg) KV chunk on one XCD.
template<int NS>
__global__ __launch_bounds__(256, 8)
void attn_fwd9(const float* __restrict__ qg, const float* __restrict__ mg,
               const short* __restrict__ kp, const short* __restrict__ vtp,
               float* __restrict__ outg,
               short* __restrict__ Opart, float* __restrict__ lpart)
{
    constexpr int SEGLEN = SEQ / NS;
    constexpr int ITERS  = SEGLEN / TK;

    __shared__ __align__(16) short Kl[2][TK][DIM];   // 2 x 4 KB
    __shared__ __align__(16) short Vt[2][DIM][TK];   // 2 x 4 KB

    const int tid  = threadIdx.x;
    const int wave = tid >> 6;
    const int lane = tid & 63;
    const int ln   = lane & 15;
    const int quad = lane >> 4;

    const int qblk = blockIdx.x & 31;                // 32 q-blocks of 128 rows
    const int rest = blockIdx.x >> 5;
    const int seg  = (NS == 1) ? 0 : (rest & (NS - 1));
    const int b    = (NS == 1) ? rest : (rest / NS);

    const int qw = qblk * 128 + wave * 32;           // wave's first q row
    const size_t bbase = (size_t)b * SEQ * DIM;

    const short* kb  = kp  + bbase + (size_t)seg * SEGLEN * DIM;
    const short* vb  = vtp + bbase + (size_t)seg * SEGLEN * DIM;
    const float* mgb = mg + (size_t)b * SEQ;

    const int gs0 = quad ^ (ln & 7);                 // K-frag granule (h=0); h=1: ^4
    const int gsv = quad ^ ((ln >> 1) & 3);          // V-frag granule

    // loop-invariant Q B-frags (x32 QK): B[k=quad*8+j][n=ln], scale 0.125*log2e
    bf16x8 aq[2][2];
    #pragma unroll
    for (int qt = 0; qt < 2; ++qt) {
        const float* qrow = qg + bbase + (size_t)(qw + qt * 16 + ln) * DIM;
        #pragma unroll
        for (int h = 0; h < 2; ++h) {
            alignas(16) short tmp[8];
            #pragma unroll
            for (int j = 0; j < 8; ++j)
                tmp[j] = f2bf(qrow[quad * 8 + h * 32 + j] * (0.125f * LOG2E));
            aq[qt][h] = *reinterpret_cast<bf16x8*>(tmp);
        }
    }

    f32x4 O[2][4];               // [q-tile][ds]; lane: d = ds*16+quad*4+r, q = qw+qt*16+ln
    float lacc[2] = {0.f, 0.f};
    #pragma unroll
    for (int qt = 0; qt < 2; ++qt)
        #pragma unroll
        for (int i = 0; i < 4; ++i) O[qt][i] = (f32x4){0.f, 0.f, 0.f, 0.f};

    // prologue DMA: tile 0 -> buf 0 (wave w: 1 KB K chunk w + 1 KB V chunk w)
    async16(kb + wave * 512 + lane * 8, &Kl[0][0][0] + wave * 512);
    async16(vb + wave * 512 + lane * 8, &Vt[0][0][0] + wave * 512);

    for (int t = 0; t < ITERS; ++t) {
        const int buf = t & 1;
        asm volatile("s_waitcnt vmcnt(0)" ::: "memory");
        __syncthreads();

        if (t + 1 < ITERS) {
            const short* gk = kb + (size_t)(t + 1) * TK * DIM;
            const short* gv = vb + (size_t)(t + 1) * TK * DIM;
            async16(gk + wave * 512 + lane * 8, &Kl[buf ^ 1][0][0] + wave * 512);
            async16(gv + wave * 512 + lane * 8, &Vt[buf ^ 1][0][0] + wave * 512);
        }

        const int key0 = seg * SEGLEN + t * TK;
        const short* klb = &Kl[buf][0][0];
        const short* vtb = &Vt[buf][0][0];

        // masks: keys key0 + v*16 + quad*4 + {0..3}
        f32x4 m4[2];
        #pragma unroll
        for (int v = 0; v < 2; ++v)
            m4[v] = *reinterpret_cast<const f32x4*>(mgb + key0 + v * 16 + quad * 4);

        // ---- K.Q^T: sf[qt][v][r] = S^T[key = v*16+quad*4+r][q = qw+qt*16+ln] ----
        f32x4 sf[2][2];
        #pragma unroll
        for (int v = 0; v < 2; ++v) {
            bf16x8 ka0 = *reinterpret_cast<const bf16x8*>(
                klb + (v * 16 + ln) * DIM + gs0 * 8);
            bf16x8 ka1 = *reinterpret_cast<const bf16x8*>(
                klb + (v * 16 + ln) * DIM + (gs0 ^ 4) * 8);
            #pragma unroll
            for (int qt = 0; qt < 2; ++qt) {
                f32x4 acc = (f32x4){0.f, 0.f, 0.f, 0.f};
                acc = __builtin_amdgcn_mfma_f32_16x16x32_bf16(ka0, aq[qt][0], acc, 0, 0, 0);
                acc = __builtin_amdgcn_mfma_f32_16x16x32_bf16(ka1, aq[qt][1], acc, 0, 0, 0);
                sf[qt][v] = acc;
            }
        }

        // ---- p = exp2(s); l += p*mask; pack to x16 B-frags (identity layout) ----
        bf16x4 bp[2][2];
        #pragma unroll
        for (int qt = 0; qt < 2; ++qt) {
            #pragma unroll
            for (int v = 0; v < 2; ++v) {
                #pragma unroll
                for (int r = 0; r < 4; ++r) {
                    sf[qt][v][r] = EXP2(sf[qt][v][r]);
                    lacc[qt] = fmaf(sf[qt][v][r], m4[v][r], lacc[qt]);
                }
                bp[qt][v] = mk4(sf[qt][v]);
            }
        }

        // ---- PV: per ds one b128 -> A-frags for both k-steps ----
        #pragma unroll
        for (int ds = 0; ds < 4; ++ds) {
            bf16x8 vf = *reinterpret_cast<const bf16x8*>(
                vtb + (ds * 16 + ln) * TK + gsv * 8);
            bf16x4 va0 = __builtin_shufflevector(vf, vf, 0, 1, 2, 3);   // keys 0..15 slice
            bf16x4 va1 = __builtin_shufflevector(vf, vf, 4, 5, 6, 7);   // keys 16..31 slice
            #pragma unroll
            for (int qt = 0; qt < 2; ++qt) {
                O[qt][ds] = mfma16(va0, bp[qt][0], O[qt][ds]);
                O[qt][ds] = mfma16(va1, bp[qt][1], O[qt][ds]);
            }
        }
    }

    // ---- epilogue ----
    #pragma unroll
    for (int qt = 0; qt < 2; ++qt) {
        lacc[qt] += __shfl_xor(lacc[qt], 16);
        lacc[qt] += __shfl_xor(lacc[qt], 32);
    }

    if (NS == 1) {
        #pragma unroll
        for (int qt = 0; qt < 2; ++qt) {
            const int qrow_i = qw + qt * 16 + ln;
            const float qm = mgb[qrow_i];
            const float inv = 1.0f / lacc[qt];
            const float* qrow = qg + bbase + (size_t)qrow_i * DIM;
            float* orow = outg + bbase + (size_t)qrow_i * DIM;
            #pragma unroll
            for (int ds = 0; ds < 4; ++ds) {
                const int d0 = ds * 16 + quad * 4;
                f32x4 o4;
                #pragma unroll
                for (int r = 0; r < 4; ++r) o4[r] = O[qt][ds][r] * inv;
                if (qm == 0.0f) {
                    f32x4 q4 = *reinterpret_cast<const f32x4*>(qrow + d0);
                    #pragma unroll
                    for (int r = 0; r < 4; ++r) o4[r] = q4[r] * 0.125f;
                }
                *reinterpret_cast<f32x4*>(orow + d0) = o4;
            }
        }
    } else {
        // bf16 partial O [seg][gq][64] + fp32 l [seg][gq]
        #pragma unroll
        for (int qt = 0; qt < 2; ++qt) {
            const int gq = b * SEQ + qw + qt * 16 + ln;
            short* ob = Opart + ((size_t)seg * TOTQ + gq) * 64;
            #pragma unroll
            for (int ds = 0; ds < 2; ++ds) {
                bf16x4 lo = mk4(O[qt][ds * 2 + 0]);
                bf16x4 hi = mk4(O[qt][ds * 2 + 1]);
                *reinterpret_cast<bf16x4*>(ob + (ds * 2 + 0) * 16 + quad * 4) = lo;
                *reinterpret_cast<bf16x4*>(ob + (ds * 2 + 1) * 16 + quad * 4) = hi;
            }
            if (quad == 0) lpart[(size_t)seg * TOTQ + gq] = lacc[qt];
        }
    }
}

// ---------------- combine partials (separate dispatch — no device fences) ------
template<int NS>
__global__ __launch_bounds__(256)
void combine_p(const short* __restrict__ Opart, const float* __restrict__ lpart,
               const float* __restrict__ qg, const float* __restrict__ mg,
               float* __restrict__ outg)
{
    const int t = blockIdx.x * 256 + threadIdx.x;   // TOTQ*16 threads, float4 each
    const int gq = t >> 4;
    const int d0 = (t & 15) * 4;
    float a0 = 0.f, a1 = 0.f, a2 = 0.f, a3 = 0.f, den = 0.f;
    #pragma unroll
    for (int s = 0; s < NS; ++s) {
        const short* ob = Opart + ((size_t)s * TOTQ + gq) * 64 + d0;
        short4 o4 = *reinterpret_cast<const short4*>(ob);
        a0 += bf2f(o4.x); a1 += bf2f(o4.y);
        a2 += bf2f(o4.z); a3 += bf2f(o4.w);
        den += lpart[(size_t)s * TOTQ + gq];
    }
    const float inv = 1.0f / den;
    f32x4 o;
    o[0] = a0 * inv; o[1] = a1 * inv; o[2] = a2 * inv; o[3] = a3 * inv;
    if (mg[gq] == 0.0f) {
        f32x4 q4 = *reinterpret_cast<const f32x4*>(qg + (size_t)gq * DIM + d0);
        #pragma unroll
        for (int r = 0; r < 4; ++r) o[r] = q4[r] * 0.125f;
    }
    *reinterpret_cast<f32x4*>(outg + (size_t)gq * DIM + d0) = o;
}

extern "C" void kernel_launch(void* const* d_in, const int* in_sizes, int n_in,
                              void* d_out, int out_size, void* d_ws, size_t ws_size,
                              hipStream_t stream) {
    (void)in_sizes; (void)n_in; (void)out_size;
    const float* q = (const float*)d_in[0];
    const float* k = (const float*)d_in[1];
    const float* v = (const float*)d_in[2];
    const float* m = (const float*)d_in[3];
    float* out = (float*)d_out;

    const size_t nelem  = (size_t)BATCH * SEQ * DIM;                 // 1M
    const size_t packsz = nelem * 2 * sizeof(short);                 // 4 MB
    const size_t osz    = (size_t)NSEG * TOTQ * 64 * sizeof(short);  // 32 MB
    const size_t lsz    = (size_t)NSEG * TOTQ * sizeof(float);       // 1 MB

    short* kp  = (short*)d_ws;
    short* vtp = kp + nelem;
    short* Op  = (short*)((char*)d_ws + packsz);
    float* lp  = (float*)((char*)d_ws + packsz + osz);

    pack_kv<<<dim3(512), dim3(256), 0, stream>>>(k, v, m, kp, vtp);

    if (ws_size >= packsz + osz + lsz) {
        attn_fwd9<NSEG><<<dim3(BATCH * 32 * NSEG), dim3(256), 0, stream>>>(
            q, m, kp, vtp, out, Op, lp);
        combine_p<NSEG><<<dim3(TOTQ * 16 / 256), dim3(256), 0, stream>>>(
            Op, lp, q, m, out);
    } else {
        attn_fwd9<1><<<dim3(BATCH * 32), dim3(256), 0, stream>>>(
            q, m, kp, vtp, out, nullptr, nullptr);
    }
}

// Round 10
// 106.020 us; speedup vs baseline: 2.1710x; 2.1710x over previous
//
#include <hip/hip_runtime.h>
#include <hip/hip_bf16.h>

#define BATCH 4
#define SEQ   4096
#define DIM   64
#define TK    64               // keys per LDS tile
#define TOTQ  (BATCH * SEQ)    // 16384
#define LOG2E 1.4426950408889634f

#if __has_builtin(__builtin_amdgcn_mfma_f32_16x16x16bf16_1k)
#define HAVE_1K 1
#else
#define HAVE_1K 0              // inline-asm v_mfma_f32_16x16x16_bf16 (ISA-confirmed gfx950)
#endif

#if __has_builtin(__builtin_amdgcn_exp2f)
#define EXP2(x) __builtin_amdgcn_exp2f(x)
#else
#define EXP2(x) exp2f(x)
#endif

typedef __attribute__((ext_vector_type(8))) short bf16x8;   // 4 VGPR frag (x32 MFMA A/B)
typedef __attribute__((ext_vector_type(4))) short bf16x4;   // 2 VGPR frag (x16 MFMA A/B)
typedef __attribute__((ext_vector_type(4))) float f32x4;    // MFMA C/D frag

#define AS1 __attribute__((address_space(1)))
#define AS3 __attribute__((address_space(3)))

static __device__ __forceinline__ short f2bf(float x) {
    __hip_bfloat16 h = __float2bfloat16(x);
    return *reinterpret_cast<short*>(&h);
}
static __device__ __forceinline__ float bf2f(short s) {
    unsigned int u = ((unsigned int)(unsigned short)s) << 16;
    float f; __builtin_memcpy(&f, &u, 4); return f;
}
static __device__ __forceinline__ int pk2bf(float lo, float hi) {
    __hip_bfloat162 t = __float22bfloat162_rn(make_float2(lo, hi));
    int r; __builtin_memcpy(&r, &t, 4); return r;
}
static __device__ __forceinline__ bf16x4 mk4(const f32x4& s) {
    int2 t = make_int2(pk2bf(s[0], s[1]), pk2bf(s[2], s[3]));
    bf16x4 r; __builtin_memcpy(&r, &t, 8); return r;
}
static __device__ __forceinline__ f32x4 mfma16(bf16x4 a, bf16x4 b, f32x4 c) {
#if HAVE_1K
    return __builtin_amdgcn_mfma_f32_16x16x16bf16_1k(a, b, c, 0, 0, 0);
#else
    asm("v_mfma_f32_16x16x16_bf16 %0, %1, %2, %0" : "+v"(c) : "v"(a), "v"(b));
    return c;
#endif
}
static __device__ __forceinline__ void async16(const short* g, short* l) {
    __builtin_amdgcn_global_load_lds((const AS1 unsigned int*)g,
                                     (AS3 unsigned int*)l, 16, 0, 0);
}

// ---------------- pack pre-pass (identical to R6/R8 — proven) ----------------
__global__ __launch_bounds__(256)
void pack_kv(const float* __restrict__ kg, const float* __restrict__ vg,
             const float* __restrict__ mg,
             short* __restrict__ kp, short* __restrict__ vtp)
{
    if (blockIdx.x < 256) {                            // ---- K: 4 float4 / thread ----
        #pragma unroll
        for (int i = 0; i < 4; ++i) {
            const int unit = blockIdx.x * 1024 + i * 256 + threadIdx.x;
            const int row = unit >> 4;
            const int d0  = (unit & 15) * 4;
            f32x4 kv = *reinterpret_cast<const f32x4*>(kg + (size_t)row * DIM + d0);
            short4 ks;
            ks.x = f2bf(kv[0]); ks.y = f2bf(kv[1]); ks.z = f2bf(kv[2]); ks.w = f2bf(kv[3]);
            const int gs = (d0 >> 3) ^ (row & 7);
            *reinterpret_cast<short4*>(kp + (size_t)row * DIM + gs * 8 + (d0 & 7)) = ks;
        }
    } else {                                           // ---- V: one 64-key tile / block ----
        __shared__ float Vl[64][66];
        __shared__ float Ml[64];
        const int tile = blockIdx.x - 256;
        const float* src = vg + (size_t)tile * TK * DIM;
        const int tid = threadIdx.x;
        #pragma unroll
        for (int i = 0; i < 4; ++i) {
            int idx = i * 256 + tid;
            int key = idx >> 4, part = idx & 15;
            f32x4 vv = *reinterpret_cast<const f32x4*>(src + (size_t)key * DIM + part * 4);
            float2* p0 = reinterpret_cast<float2*>(&Vl[key][part * 4]);
            p0[0] = make_float2(vv[0], vv[1]);
            p0[1] = make_float2(vv[2], vv[3]);
        }
        if (tid < 64) Ml[tid] = mg[(size_t)tile * TK + tid];
        __syncthreads();
        #pragma unroll
        for (int i = 0; i < 2; ++i) {
            const int gid = i * 256 + tid;
            const int d = gid >> 3;
            const int G = gid & 7;           // G = qd*2 + u
            const int qd = G >> 1, u = G & 1;
            alignas(16) short s8[8];
            #pragma unroll
            for (int e = 0; e < 8; ++e) {    // e = v*4 + j
                const int v = e >> 2, j = e & 3;
                const int key = (2 * u + v) * 16 + qd * 4 + j;
                s8[e] = f2bf(Vl[key][d] * Ml[key]);
            }
            const int Gs = G ^ (d & 7);
            short* dst = vtp + (size_t)tile * (TK * DIM) + d * TK + Gs * 8;
            *reinterpret_cast<int4*>(dst) = *reinterpret_cast<const int4*>(s8);
        }
    }
}

// ---------------- main attention kernel (R8 core + XCD-colocated KV sharers) ----
// S^T orientation; Q pre-scaled 0.125*log2e so p = exp2(s); V pre-masked;
// PV via 16x16x16 MFMA (S^T C-layout == P^T B-layout, no cross-lane move).
// NSEG==8 decode puts seg in blockIdx%8: all 32 qblk-sharers of one (b,seg)
// KV chunk land on ONE XCD (round-robin heuristic) -> 512 KB KV/XCD, L2-resident.
template<int NS>
__global__ __launch_bounds__(256, 4)
void attn_fwd10(const float* __restrict__ qg, const float* __restrict__ mg,
                const short* __restrict__ kp, const short* __restrict__ vtp,
                float* __restrict__ outg,
                short* __restrict__ Opart, float* __restrict__ lpart)
{
    constexpr int SEGLEN = SEQ / NS;
    constexpr int ITERS  = SEGLEN / TK;

    __shared__ __align__(16) short Kl[2][TK][DIM];   // 2 x 8 KB
    __shared__ __align__(16) short Vt[2][DIM][TK];   // 2 x 8 KB

    const int tid  = threadIdx.x;
    const int wave = tid >> 6;
    const int lane = tid & 63;
    const int ln   = lane & 15;
    const int quad = lane >> 4;

    const int x = blockIdx.x;
    int qblk, seg, b;
    if (NS == 8) {
        // XCD-colocation permutation (bijective on [0,1024)):
        //   x = seg + 8*(qblk + 32*b)  ->  x%8 == seg for all sharers of (b,seg)
        seg  = x & 7;
        qblk = (x >> 3) & 31;
        b    = x >> 8;
    } else {
        qblk = x & 31;
        const int rest = x >> 5;
        seg = (NS == 1) ? 0 : (rest & (NS - 1));
        b   = (NS == 1) ? rest : (rest / NS);
    }

    const int qw = qblk * 128 + wave * 32;           // wave's first q row
    const size_t bbase = (size_t)b * SEQ * DIM;

    const short* kb  = kp  + bbase + (size_t)seg * SEGLEN * DIM;
    const short* vb  = vtp + bbase + (size_t)seg * SEGLEN * DIM;
    const float* mgb = mg + (size_t)b * SEQ;

    const int gs0 = quad ^ (ln & 7);                 // K-frag granule (h=0); h=1: ^4

    // loop-invariant Q B-frags (x32 QK): B[k=quad*8+j][n=ln], scale 0.125*log2e
    bf16x8 aq[2][2];
    #pragma unroll
    for (int qt = 0; qt < 2; ++qt) {
        const float* qrow = qg + bbase + (size_t)(qw + qt * 16 + ln) * DIM;
        #pragma unroll
        for (int h = 0; h < 2; ++h) {
            alignas(16) short tmp[8];
            #pragma unroll
            for (int j = 0; j < 8; ++j)
                tmp[j] = f2bf(qrow[quad * 8 + h * 32 + j] * (0.125f * LOG2E));
            aq[qt][h] = *reinterpret_cast<bf16x8*>(tmp);
        }
    }

    f32x4 O[2][4];               // [q-tile][ds]; lane: d = ds*16+quad*4+r, q = qw+qt*16+ln
    float lacc[2] = {0.f, 0.f};
    #pragma unroll
    for (int qt = 0; qt < 2; ++qt)
        #pragma unroll
        for (int i = 0; i < 4; ++i) O[qt][i] = (f32x4){0.f, 0.f, 0.f, 0.f};

    // prologue DMA: tile 0 -> buf 0
    #pragma unroll
    for (int i = 0; i < 2; ++i) {
        const int c = wave * 2 + i;
        async16(kb + c * 512 + lane * 8, &Kl[0][0][0] + c * 512);
        async16(vb + c * 512 + lane * 8, &Vt[0][0][0] + c * 512);
    }

    for (int t = 0; t < ITERS; ++t) {
        const int buf = t & 1;
        asm volatile("s_waitcnt vmcnt(0)" ::: "memory");
        __syncthreads();

        if (t + 1 < ITERS) {
            const short* gk = kb + (size_t)(t + 1) * TK * DIM;
            const short* gv = vb + (size_t)(t + 1) * TK * DIM;
            #pragma unroll
            for (int i = 0; i < 2; ++i) {
                const int c = wave * 2 + i;
                async16(gk + c * 512 + lane * 8, &Kl[buf ^ 1][0][0] + c * 512);
                async16(gv + c * 512 + lane * 8, &Vt[buf ^ 1][0][0] + c * 512);
            }
        }

        const int key0 = seg * SEGLEN + t * TK;
        const short* klb = &Kl[buf][0][0];
        const short* vtb = &Vt[buf][0][0];

        #pragma unroll
        for (int u = 0; u < 2; ++u) {
            f32x4 m4[2];
            #pragma unroll
            for (int v = 0; v < 2; ++v)
                m4[v] = *reinterpret_cast<const f32x4*>(
                    mgb + key0 + (2 * u + v) * 16 + quad * 4);

            // ---- K.Q^T ----
            f32x4 sf[2][2];
            #pragma unroll
            for (int v = 0; v < 2; ++v) {
                const int s = 2 * u + v;
                bf16x8 ka0 = *reinterpret_cast<const bf16x8*>(
                    klb + (s * 16 + ln) * DIM + gs0 * 8);
                bf16x8 ka1 = *reinterpret_cast<const bf16x8*>(
                    klb + (s * 16 + ln) * DIM + (gs0 ^ 4) * 8);
                #pragma unroll
                for (int qt = 0; qt < 2; ++qt) {
                    f32x4 acc = (f32x4){0.f, 0.f, 0.f, 0.f};
                    acc = __builtin_amdgcn_mfma_f32_16x16x32_bf16(ka0, aq[qt][0], acc, 0, 0, 0);
                    acc = __builtin_amdgcn_mfma_f32_16x16x32_bf16(ka1, aq[qt][1], acc, 0, 0, 0);
                    sf[qt][v] = acc;
                }
            }

            // ---- p = exp2(s); l += p*mask; pack ----
            bf16x4 bp[2][2];
            #pragma unroll
            for (int qt = 0; qt < 2; ++qt) {
                #pragma unroll
                for (int v = 0; v < 2; ++v) {
                    #pragma unroll
                    for (int r = 0; r < 4; ++r) {
                        sf[qt][v][r] = EXP2(sf[qt][v][r]);
                        lacc[qt] = fmaf(sf[qt][v][r], m4[v][r], lacc[qt]);
                    }
                    bp[qt][v] = mk4(sf[qt][v]);
                }
            }

            // ---- PV ----
            const int gvu = (quad * 2 + u) ^ (ln & 7);
            #pragma unroll
            for (int ds = 0; ds < 4; ++ds) {
                bf16x8 vf = *reinterpret_cast<const bf16x8*>(
                    vtb + (ds * 16 + ln) * TK + gvu * 8);
                bf16x4 va0 = __builtin_shufflevector(vf, vf, 0, 1, 2, 3);
                bf16x4 va1 = __builtin_shufflevector(vf, vf, 4, 5, 6, 7);
                #pragma unroll
                for (int qt = 0; qt < 2; ++qt) {
                    O[qt][ds] = mfma16(va0, bp[qt][0], O[qt][ds]);
                    O[qt][ds] = mfma16(va1, bp[qt][1], O[qt][ds]);
                }
            }
        }
    }

    // ---- epilogue ----
    #pragma unroll
    for (int qt = 0; qt < 2; ++qt) {
        lacc[qt] += __shfl_xor(lacc[qt], 16);
        lacc[qt] += __shfl_xor(lacc[qt], 32);
    }

    if (NS == 1) {
        #pragma unroll
        for (int qt = 0; qt < 2; ++qt) {
            const int qrow_i = qw + qt * 16 + ln;
            const float qm = mgb[qrow_i];
            const float inv = 1.0f / lacc[qt];
            const float* qrow = qg + bbase + (size_t)qrow_i * DIM;
            float* orow = outg + bbase + (size_t)qrow_i * DIM;
            #pragma unroll
            for (int ds = 0; ds < 4; ++ds) {
                const int d0 = ds * 16 + quad * 4;
                f32x4 o4;
                #pragma unroll
                for (int r = 0; r < 4; ++r) o4[r] = O[qt][ds][r] * inv;
                if (qm == 0.0f) {
                    f32x4 q4 = *reinterpret_cast<const f32x4*>(qrow + d0);
                    #pragma unroll
                    for (int r = 0; r < 4; ++r) o4[r] = q4[r] * 0.125f;
                }
                *reinterpret_cast<f32x4*>(orow + d0) = o4;
            }
        }
    } else {
        // bf16 partial O [seg][gq][64] + fp32 l [seg][gq]
        #pragma unroll
        for (int qt = 0; qt < 2; ++qt) {
            const int gq = b * SEQ + qw + qt * 16 + ln;
            short* ob = Opart + ((size_t)seg * TOTQ + gq) * 64;
            #pragma unroll
            for (int ds = 0; ds < 2; ++ds) {
                bf16x4 lo = mk4(O[qt][ds * 2 + 0]);
                bf16x4 hi = mk4(O[qt][ds * 2 + 1]);
                *reinterpret_cast<bf16x4*>(ob + (ds * 2 + 0) * 16 + quad * 4) = lo;
                *reinterpret_cast<bf16x4*>(ob + (ds * 2 + 1) * 16 + quad * 4) = hi;
            }
            if (quad == 0) lpart[(size_t)seg * TOTQ + gq] = lacc[qt];
        }
    }
}

// ---------------- combine partials (separate dispatch — no device fences) ------
template<int NS>
__global__ __launch_bounds__(256)
void combine_p(const short* __restrict__ Opart, const float* __restrict__ lpart,
               const float* __restrict__ qg, const float* __restrict__ mg,
               float* __restrict__ outg)
{
    const int t = blockIdx.x * 256 + threadIdx.x;   // TOTQ*16 threads, float4 each
    const int gq = t >> 4;
    const int d0 = (t & 15) * 4;
    float a0 = 0.f, a1 = 0.f, a2 = 0.f, a3 = 0.f, den = 0.f;
    #pragma unroll
    for (int s = 0; s < NS; ++s) {
        const short* ob = Opart + ((size_t)s * TOTQ + gq) * 64 + d0;
        short4 o4 = *reinterpret_cast<const short4*>(ob);
        a0 += bf2f(o4.x); a1 += bf2f(o4.y);
        a2 += bf2f(o4.z); a3 += bf2f(o4.w);
        den += lpart[(size_t)s * TOTQ + gq];
    }
    const float inv = 1.0f / den;
    f32x4 o;
    o[0] = a0 * inv; o[1] = a1 * inv; o[2] = a2 * inv; o[3] = a3 * inv;
    if (mg[gq] == 0.0f) {
        f32x4 q4 = *reinterpret_cast<const f32x4*>(qg + (size_t)gq * DIM + d0);
        #pragma unroll
        for (int r = 0; r < 4; ++r) o[r] = q4[r] * 0.125f;
    }
    *reinterpret_cast<f32x4*>(outg + (size_t)gq * DIM + d0) = o;
}

extern "C" void kernel_launch(void* const* d_in, const int* in_sizes, int n_in,
                              void* d_out, int out_size, void* d_ws, size_t ws_size,
                              hipStream_t stream) {
    (void)in_sizes; (void)n_in; (void)out_size;
    const float* q = (const float*)d_in[0];
    const float* k = (const float*)d_in[1];
    const float* v = (const float*)d_in[2];
    const float* m = (const float*)d_in[3];
    float* out = (float*)d_out;

    const size_t nelem  = (size_t)BATCH * SEQ * DIM;            // 1M
    const size_t packsz = nelem * 2 * sizeof(short);            // 4 MB
    const size_t osz    = (size_t)8 * TOTQ * 64 * sizeof(short);// 16 MB
    const size_t lsz    = (size_t)8 * TOTQ * sizeof(float);     // 512 KB

    short* kp  = (short*)d_ws;
    short* vtp = kp + nelem;
    short* Op  = (short*)((char*)d_ws + packsz);
    float* lp  = (float*)((char*)d_ws + packsz + osz);

    pack_kv<<<dim3(512), dim3(256), 0, stream>>>(k, v, m, kp, vtp);

    if (ws_size >= packsz + osz + lsz) {
        attn_fwd10<8><<<dim3(BATCH * 32 * 8), dim3(256), 0, stream>>>(
            q, m, kp, vtp, out, Op, lp);
        combine_p<8><<<dim3(TOTQ * 16 / 256), dim3(256), 0, stream>>>(
            Op, lp, q, m, out);
    } else {
        attn_fwd10<1><<<dim3(BATCH * 32), dim3(256), 0, stream>>>(
            q, m, kp, vtp, out, nullptr, nullptr);
    }
}